// Round 8
// baseline (248.448 us; speedup 1.0000x reference)
//
#include <hip/hip_runtime.h>
#include <hip/hip_bf16.h>
#include <cstdint>
#include <math.h>

using bf16 = __hip_bfloat16;
typedef __attribute__((ext_vector_type(8))) short bf16x8;
typedef __attribute__((ext_vector_type(4))) float f32x4;

#define DEV __device__ __forceinline__

DEV float b2f(unsigned short u) { return __uint_as_float(((uint32_t)u) << 16); }
DEV float bfl(bf16 h) { return __bfloat162float(h); }
DEV short f2bs(float f) { bf16 h = __float2bfloat16(f); return *(short*)&h; }
// explicit bf16-pair pack: a in low 16 bits (lower address), b in high.
DEV uint32_t pk2(float a, float b) {
  return (uint32_t)(unsigned short)f2bs(a) |
         ((uint32_t)(unsigned short)f2bs(b) << 16);
}
DEV float ldv(const void* p, int isbf, int i) {
  return isbf ? bfl(((const bf16*)p)[i]) : ((const float*)p)[i];
}

// weight fragment: 8 contiguous elems at w[row*K + off] -> bf16x8
DEV bf16x8 load_wfrag(const void* w, int isbf, int row, int K, int off) {
  bf16x8 r;
  if (isbf) {
    r = *(const bf16x8*)((const short*)w + (size_t)row * K + off);
  } else {
    const float* f = (const float*)w + (size_t)row * K + off;
    float4 a = *(const float4*)f, b = *(const float4*)(f + 4);
    r[0] = f2bs(a.x); r[1] = f2bs(a.y); r[2] = f2bs(a.z); r[3] = f2bs(a.w);
    r[4] = f2bs(b.x); r[5] = f2bs(b.y); r[6] = f2bs(b.z); r[7] = f2bs(b.w);
  }
  return r;
}

// ---------------------------------------------------------------------------
// dtype sniffer — validated.
// ---------------------------------------------------------------------------
__global__ __launch_bounds__(256) void sniff_kernel(
    const unsigned short* __restrict__ xr, int* __restrict__ flag)
{
  int tid = threadIdx.x;
  int good = 0;
  for (int k = tid; k < 16384; k += 256) {
    unsigned short u = xr[2 * k];
    int e = (u >> 7) & 0xFF;
    good += (e >= 0x6A && e <= 0x86) ? 1 : 0;
  }
  __shared__ int r[256];
  r[tid] = good;
  __syncthreads();
  for (int off = 128; off; off >>= 1) {
    if (tid < off) r[tid] += r[tid + off];
    __syncthreads();
  }
  if (tid == 0) *flag = (r[0] > 9830) ? 1 : 0;
}

// ---------------------------------------------------------------------------
// transpose x [b][c(256)][n(4096)] (flag dtype) -> xT [b][n][c] bf16.
// Validated (R3/R7).
// ---------------------------------------------------------------------------
__global__ __launch_bounds__(256) void transpose_x(
    const void* __restrict__ x, short* __restrict__ xT, const int* __restrict__ flag)
{
  const int isbf = *flag;
  __shared__ short lt[64 * 71];
  const int n0 = blockIdx.x * 64, c0 = blockIdx.y * 64, b = blockIdx.z;
  const int tid = threadIdx.x;
  for (int it = 0; it < 4; ++it) {
    int idx4 = it * 256 + tid;
    int ci = idx4 >> 4, n4 = (idx4 & 15) * 4;
    size_t go = ((size_t)(b * 256 + c0 + ci)) * 4096 + n0 + n4;
    if (isbf) {
      ushort4 v = *(const ushort4*)((const unsigned short*)x + go);
      lt[ci * 71 + n4 + 0] = v.x; lt[ci * 71 + n4 + 1] = v.y;
      lt[ci * 71 + n4 + 2] = v.z; lt[ci * 71 + n4 + 3] = v.w;
    } else {
      float4 v = *(const float4*)((const float*)x + go);
      lt[ci * 71 + n4 + 0] = f2bs(v.x); lt[ci * 71 + n4 + 1] = f2bs(v.y);
      lt[ci * 71 + n4 + 2] = f2bs(v.z); lt[ci * 71 + n4 + 3] = f2bs(v.w);
    }
  }
  __syncthreads();
  for (int it = 0; it < 4; ++it) {
    int idx4 = it * 256 + tid;
    int n = idx4 >> 4, c4 = (idx4 & 15) * 4;
    ushort4 v;
    v.x = (unsigned short)lt[(c4 + 0) * 71 + n];
    v.y = (unsigned short)lt[(c4 + 1) * 71 + n];
    v.z = (unsigned short)lt[(c4 + 2) * 71 + n];
    v.w = (unsigned short)lt[(c4 + 3) * 71 + n];
    *(ushort4*)(xT + ((size_t)(b * 4096 + n0 + n)) * 256 + c0 + c4) = v;
  }
}

// ---------------------------------------------------------------------------
// conv_t: out[b][n][co=128] — validated (R3/R7).
// ---------------------------------------------------------------------------
__global__ __launch_bounds__(256) void conv_t_k(
    const short* __restrict__ xT, const void* __restrict__ w,
    const void* __restrict__ bias, short* __restrict__ out,
    const int* __restrict__ flag)
{
  const int isbf = *flag;
  __shared__ short sh[64 * 264];
  const int b = blockIdx.y, nbase = blockIdx.x * 64, tid = threadIdx.x;
  const int ln = tid & 15, q = (tid >> 4) & 3, wv = tid >> 6;
  for (int it = 0; it < 16; ++it) {
    int idx4 = it * 256 + tid;
    int n = idx4 >> 6, c4 = (idx4 & 63) * 4;
    *(ushort4*)&sh[n * 264 + c4] =
        *(const ushort4*)(xT + ((size_t)(b * 4096 + nbase + n)) * 256 + c4);
  }
  __syncthreads();
  f32x4 zero = {0.f, 0.f, 0.f, 0.f};
  f32x4 acc[4][2];
  for (int nt = 0; nt < 4; ++nt) for (int ti = 0; ti < 2; ++ti) acc[nt][ti] = zero;

  for (int kk = 0; kk < 8; ++kk) {
    int off = kk * 32 + q * 8;
    bf16x8 a[4];
    #pragma unroll
    for (int nt = 0; nt < 4; ++nt)
      a[nt] = *(const bf16x8*)&sh[(16 * nt + ln) * 264 + off];
    #pragma unroll
    for (int ti = 0; ti < 2; ++ti) {
      bf16x8 bw = load_wfrag(w, isbf, 16 * (2 * wv + ti) + ln, 256, off);
      #pragma unroll
      for (int nt = 0; nt < 4; ++nt)
        acc[nt][ti] = __builtin_amdgcn_mfma_f32_16x16x32_bf16(a[nt], bw, acc[nt][ti], 0, 0, 0);
    }
  }
  __syncthreads();
  float bv[2];
  for (int ti = 0; ti < 2; ++ti) bv[ti] = ldv(bias, isbf, 16 * (2 * wv + ti) + ln);
  for (int nt = 0; nt < 4; ++nt)
    for (int ti = 0; ti < 2; ++ti)
      for (int r = 0; r < 4; ++r)
        sh[(16 * nt + q * 4 + r) * 136 + 16 * (2 * wv + ti) + ln] =
            f2bs(acc[nt][ti][r] + bv[ti]);
  __syncthreads();
  for (int it = 0; it < 8; ++it) {
    int idx4 = it * 256 + tid;
    int n = idx4 >> 5, c4 = (idx4 & 31) * 4;
    *(ushort4*)(out + ((size_t)(b * 4096 + nbase + n)) * 128 + c4) =
        *(const ushort4*)&sh[n * 136 + c4];
  }
}

// ---------------------------------------------------------------------------
// conv_n: out[b][CO][n] — validated (R3/R7).
// ---------------------------------------------------------------------------
template<int CO, int K>
__global__ __launch_bounds__(256) void conv_n_k(
    const short* __restrict__ inp, const void* __restrict__ w,
    const void* __restrict__ bias, short* __restrict__ out,
    const int* __restrict__ flag)
{
  const int isbf = *flag;
  constexpr int XS = 64 * (K + 8);
  constexpr int OS = CO * 68;
  __shared__ short sh[(XS > OS ? XS : OS)];
  const int b = blockIdx.y, nbase = blockIdx.x * 64, tid = threadIdx.x;
  const int ln = tid & 15, q = (tid >> 4) & 3, wv = tid >> 6;
  constexpr int TPW = CO / 64;
  constexpr int KS = (K == 256) ? 6 : 5;
  for (int it = 0; it < 64 * K / 1024; ++it) {
    int idx4 = it * 256 + tid;
    int n = idx4 >> KS, c4 = (idx4 & ((K / 4) - 1)) * 4;
    *(ushort4*)&sh[n * (K + 8) + c4] =
        *(const ushort4*)(inp + ((size_t)(b * 4096 + nbase + n)) * K + c4);
  }
  __syncthreads();
  f32x4 zero = {0.f, 0.f, 0.f, 0.f};
  f32x4 acc[TPW][4];
  for (int ti = 0; ti < TPW; ++ti) for (int nt = 0; nt < 4; ++nt) acc[ti][nt] = zero;

  for (int kk = 0; kk < K / 32; ++kk) {
    int off = kk * 32 + q * 8;
    bf16x8 bx[4];
    #pragma unroll
    for (int nt = 0; nt < 4; ++nt)
      bx[nt] = *(const bf16x8*)&sh[(16 * nt + ln) * (K + 8) + off];
    #pragma unroll
    for (int ti = 0; ti < TPW; ++ti) {
      bf16x8 aw = load_wfrag(w, isbf, 16 * (TPW * wv + ti) + ln, K, off);
      #pragma unroll
      for (int nt = 0; nt < 4; ++nt)
        acc[ti][nt] = __builtin_amdgcn_mfma_f32_16x16x32_bf16(aw, bx[nt], acc[ti][nt], 0, 0, 0);
    }
  }
  __syncthreads();
  for (int ti = 0; ti < TPW; ++ti)
    for (int r = 0; r < 4; ++r) {
      int co = 16 * (TPW * wv + ti) + q * 4 + r;
      float bb = ldv(bias, isbf, co);
      for (int nt = 0; nt < 4; ++nt)
        sh[co * 68 + 16 * nt + ln] = f2bs(acc[ti][nt][r] + bb);
    }
  __syncthreads();
  for (int it = 0; it < 64 * CO / 1024; ++it) {
    int idx4 = it * 256 + tid;
    int co = idx4 >> 4, n4 = (idx4 & 15) * 4;
    *(ushort4*)(out + ((size_t)(b * CO + co)) * 4096 + nbase + n4) =
        *(const ushort4*)&sh[co * 68 + n4];
  }
}

// ---------------------------------------------------------------------------
// pools — validated (R3/R7).
// ---------------------------------------------------------------------------
__global__ __launch_bounds__(256) void pool_phi_kernel(
    const short* __restrict__ pc, short* __restrict__ phi)
{
  int idx = blockIdx.x * 256 + threadIdx.x;  // b*1024*128
  int ci = idx & 127, m = (idx >> 7) & 1023, b = idx >> 17;
  int mh = m >> 5, mw = m & 31;
  const short* p = pc + ((size_t)(b * 4096 + (mh * 2) * 64 + mw * 2)) * 128 + ci;
  float v = fmaxf(fmaxf(b2f(p[0]), b2f(p[128])),
                  fmaxf(b2f(p[64 * 128]), b2f(p[65 * 128])));
  phi[idx] = f2bs(v);
}

__global__ __launch_bounds__(256) void pool_g_kernel(
    const short* __restrict__ gc, short* __restrict__ g)
{
  int idx = blockIdx.x * 256 + threadIdx.x;  // (b*128+ci)*1024 + m
  int m = idx & 1023, bc = idx >> 10;
  int mh = m >> 5, mw = m & 31;
  const short* p = gc + (size_t)bc * 4096 + mh * 128 + mw * 2;
  float v = fmaxf(fmaxf(b2f(p[0]), b2f(p[1])), fmaxf(b2f(p[64]), b2f(p[65])));
  g[idx] = f2bs(v);
}

// ---------------------------------------------------------------------------
// MFMA flash attention v2 — UNDER TEST (R4 design, exonerated by R5/R6
// identical-absmax evidence; re-audited 3x). S^T orientation (A=phi, B=theta)
// -> packed b64 P stores; theta B-frags preloaded to registers so Pl aliases
// the theta LDS (53.2 KB -> 3 blocks/CU); PV uses A=g rows, B=P; row sums
// via ones-A MFMA; uint4 staging.
// ---------------------------------------------------------------------------
__global__ __launch_bounds__(256, 3) void attn_kernel(
    const short* __restrict__ theta, const short* __restrict__ phi,
    const short* __restrict__ g, short* __restrict__ y)
{
  __shared__ short th[64 * 136];   // theta staging; later Pl [n][m] (stride 72)
  __shared__ short ph[64 * 136];   // phi chunk [m][ci]; finally y staging
  __shared__ short gl[128 * 72];   // g chunk [ci][m]
  short* Pl = th;
  const int b = blockIdx.y, nbase = blockIdx.x * 64, tid = threadIdx.x;
  const int ln = tid & 15, q = (tid >> 4) & 3, wv = tid >> 6;

  for (int it = 0; it < 4; ++it) {
    int idx8 = it * 256 + tid;
    int n = idx8 >> 4, c8 = (idx8 & 15) * 8;
    *(uint4*)&th[n * 136 + c8] =
        *(const uint4*)(theta + ((size_t)(b * 4096 + nbase + n)) * 128 + c8);
  }
  __syncthreads();
  bf16x8 bth[4][4];
  #pragma unroll
  for (int t = 0; t < 4; ++t)
    #pragma unroll
    for (int kk = 0; kk < 4; ++kk)
      bth[t][kk] = *(const bf16x8*)&th[(16 * t + ln) * 136 + kk * 32 + q * 8];

  bf16x8 onesA;
  #pragma unroll
  for (int j = 0; j < 8; ++j) onesA[j] = 0x3F80;

  f32x4 zero = {0.f, 0.f, 0.f, 0.f};
  f32x4 yacc[2][4], lacc[4];
  for (int ti = 0; ti < 2; ++ti)
    for (int t = 0; t < 4; ++t) yacc[ti][t] = zero;
  for (int t = 0; t < 4; ++t) lacc[t] = zero;

  const short* pp = phi + ((size_t)b * 1024) * 128;
  const short* gp = g + ((size_t)b * 128) * 1024;

  for (int mc = 0; mc < 16; ++mc) {
    __syncthreads();  // (A) prev chunk's gl/Pl consumed; bth preload done (mc=0)
    for (int it = 0; it < 4; ++it) {
      int idx8 = it * 256 + tid;
      int m = idx8 >> 4, c8 = (idx8 & 15) * 8;
      *(uint4*)&ph[m * 136 + c8] =
          *(const uint4*)(pp + ((size_t)(mc * 64 + m)) * 128 + c8);
    }
    for (int it = 0; it < 4; ++it) {
      int idx8 = it * 256 + tid;
      int ci = idx8 >> 3, m8 = (idx8 & 7) * 8;
      *(uint4*)&gl[ci * 72 + m8] =
          *(const uint4*)(gp + (size_t)ci * 1024 + mc * 64 + m8);
    }
    __syncthreads();  // (B) ph, gl ready

    // S^T: D[m][n], wave owns m-tile wv
    bf16x8 ap[4];
    #pragma unroll
    for (int kk = 0; kk < 4; ++kk)
      ap[kk] = *(const bf16x8*)&ph[(16 * wv + ln) * 136 + kk * 32 + q * 8];
    #pragma unroll
    for (int t = 0; t < 4; ++t) {
      f32x4 s = zero;
      #pragma unroll
      for (int kk = 0; kk < 4; ++kk)
        s = __builtin_amdgcn_mfma_f32_16x16x32_bf16(ap[kk], bth[t][kk], s, 0, 0, 0);
      uint2 uu;
      uu.x = pk2(__expf(fminf(s[0], 80.f)), __expf(fminf(s[1], 80.f)));
      uu.y = pk2(__expf(fminf(s[2], 80.f)), __expf(fminf(s[3], 80.f)));
      *(uint2*)&Pl[(16 * t + ln) * 72 + 16 * wv + 4 * q] = uu;
    }
    __syncthreads();  // (C) Pl ready (cross-wave reads follow)

    // PV: A = g rows ci (tiles 2wv, 2wv+1), B = Pl; plus l = ones^T . P
    #pragma unroll
    for (int kk = 0; kk < 2; ++kk) {
      bf16x8 bp[4], ag[2];
      #pragma unroll
      for (int t = 0; t < 4; ++t)
        bp[t] = *(const bf16x8*)&Pl[(16 * t + ln) * 72 + kk * 32 + q * 8];
      #pragma unroll
      for (int ti = 0; ti < 2; ++ti)
        ag[ti] = *(const bf16x8*)&gl[(16 * (2 * wv + ti) + ln) * 72 + kk * 32 + q * 8];
      #pragma unroll
      for (int ti = 0; ti < 2; ++ti)
        #pragma unroll
        for (int t = 0; t < 4; ++t)
          yacc[ti][t] = __builtin_amdgcn_mfma_f32_16x16x32_bf16(ag[ti], bp[t], yacc[ti][t], 0, 0, 0);
      #pragma unroll
      for (int t = 0; t < 4; ++t)
        lacc[t] = __builtin_amdgcn_mfma_f32_16x16x32_bf16(onesA, bp[t], lacc[t], 0, 0, 0);
    }
  }

  // normalize (l[n] per n-col) and stage y [n][ci] into ph.
  // Safe: last chunk's ph reads (ap) completed before sync (C); PV reads only
  // Pl/gl; per-wave ci ranges are disjoint -> no write collision.
  float li[4];
  #pragma unroll
  for (int t = 0; t < 4; ++t) li[t] = 1.0f / lacc[t][0];
  #pragma unroll
  for (int ti = 0; ti < 2; ++ti)
    #pragma unroll
    for (int t = 0; t < 4; ++t) {
      uint2 uu;
      uu.x = pk2(yacc[ti][t][0] * li[t], yacc[ti][t][1] * li[t]);
      uu.y = pk2(yacc[ti][t][2] * li[t], yacc[ti][t][3] * li[t]);
      *(uint2*)&ph[(16 * t + ln) * 136 + 32 * wv + 16 * ti + 4 * q] = uu;
    }
  __syncthreads();
  for (int it = 0; it < 4; ++it) {
    int idx8 = it * 256 + tid;
    int n = idx8 >> 4, c8 = (idx8 & 15) * 8;
    *(uint4*)(y + ((size_t)(b * 4096 + nbase + n)) * 128 + c8) =
        *(const uint4*)&ph[n * 136 + c8];
  }
}

// ---------------------------------------------------------------------------
// conv_W + BN partial-stat atomics — validated (R7).
// ---------------------------------------------------------------------------
__global__ __launch_bounds__(256, 4) void convW_k(
    const short* __restrict__ yb, const void* __restrict__ w,
    const void* __restrict__ bias, short* __restrict__ Wy,
    float* __restrict__ stats, const int* __restrict__ flag)
{
  const int isbf = *flag;
  __shared__ short sh[256 * 72];
  const int b = blockIdx.y, nbase = blockIdx.x * 64, tid = threadIdx.x;
  const int ln = tid & 15, q = (tid >> 4) & 3, wv = tid >> 6;

  for (int it = 0; it < 4; ++it) {
    int idx8 = it * 256 + tid;
    int n = idx8 >> 4, c8 = (idx8 & 15) * 8;
    *(uint4*)&sh[n * 136 + c8] =
        *(const uint4*)(yb + ((size_t)(b * 4096 + nbase + n)) * 128 + c8);
  }
  __syncthreads();
  f32x4 zero = {0.f, 0.f, 0.f, 0.f};
  f32x4 acc[4][4];
  for (int ti = 0; ti < 4; ++ti)
    for (int nt = 0; nt < 4; ++nt) acc[ti][nt] = zero;

  for (int kk = 0; kk < 4; ++kk) {
    int off = kk * 32 + q * 8;
    bf16x8 bx[4];
    #pragma unroll
    for (int nt = 0; nt < 4; ++nt)
      bx[nt] = *(const bf16x8*)&sh[(16 * nt + ln) * 136 + off];
    #pragma unroll
    for (int ti = 0; ti < 4; ++ti) {
      bf16x8 aw = load_wfrag(w, isbf, 16 * (4 * wv + ti) + ln, 128, off);
      #pragma unroll
      for (int nt = 0; nt < 4; ++nt)
        acc[ti][nt] = __builtin_amdgcn_mfma_f32_16x16x32_bf16(aw, bx[nt], acc[ti][nt], 0, 0, 0);
    }
  }
  __syncthreads();
  #pragma unroll
  for (int ti = 0; ti < 4; ++ti)
    #pragma unroll
    for (int r = 0; r < 4; ++r) {
      int co = 16 * (4 * wv + ti) + 4 * q + r;
      float bb = ldv(bias, isbf, co);
      #pragma unroll
      for (int nt = 0; nt < 4; ++nt)
        sh[co * 72 + 16 * nt + ln] = f2bs(acc[ti][nt][r] + bb);
    }
  __syncthreads();
  {
    int co = tid;
    float s = 0.f, s2 = 0.f;
    for (int i = 0; i < 64; ++i) {
      float v = b2f((unsigned short)sh[co * 72 + i]);
      s += v; s2 += v * v;
    }
    atomicAdd(&stats[co], s);
    atomicAdd(&stats[256 + co], s2);
  }
  for (int it = 0; it < 8; ++it) {
    int idx8 = it * 256 + tid;
    int co = idx8 >> 3, n8 = (idx8 & 7) * 8;
    *(uint4*)(Wy + ((size_t)(b * 256 + co)) * 4096 + nbase + n8) =
        *(const uint4*)&sh[co * 72 + n8];
  }
}

// ---------------------------------------------------------------------------
// BN apply + residual, x4 — validated (R7).
// ---------------------------------------------------------------------------
__global__ __launch_bounds__(256) void bn_apply4(
    const short* __restrict__ Wy, const void* __restrict__ x,
    const float* __restrict__ stats, const void* __restrict__ gamma,
    const void* __restrict__ beta, void* __restrict__ out,
    const int* __restrict__ flag)
{
  const int isbf = *flag;
  int t = blockIdx.x * 256 + threadIdx.x;
  int idx4 = t * 4;
  int c = (idx4 >> 12) & 255;
  float s = stats[c], s2 = stats[256 + c];
  float mean = s * (1.0f / 32768.0f);
  float var = fmaxf(s2 * (1.0f / 32768.0f) - mean * mean, 0.f);
  float scale = rsqrtf(var + 1e-5f) * ldv(gamma, isbf, c);
  float shift = ldv(beta, isbf, c) - mean * scale;
  ushort4 wy = *(const ushort4*)(Wy + idx4);
  float xv[4];
  if (isbf) {
    ushort4 xu = *(const ushort4*)((const unsigned short*)x + idx4);
    xv[0] = b2f(xu.x); xv[1] = b2f(xu.y); xv[2] = b2f(xu.z); xv[3] = b2f(xu.w);
  } else {
    float4 xf = *(const float4*)((const float*)x + idx4);
    xv[0] = xf.x; xv[1] = xf.y; xv[2] = xf.z; xv[3] = xf.w;
  }
  float v0 = b2f(wy.x) * scale + shift + xv[0];
  float v1 = b2f(wy.y) * scale + shift + xv[1];
  float v2 = b2f(wy.z) * scale + shift + xv[2];
  float v3 = b2f(wy.w) * scale + shift + xv[3];
  if (isbf) {
    uint2 o; o.x = pk2(v0, v1); o.y = pk2(v2, v3);
    *(uint2*)((unsigned short*)out + idx4) = o;
  } else {
    float4 o = make_float4(v0, v1, v2, v3);
    *(float4*)((float*)out + idx4) = o;
  }
}

// ---------------------------------------------------------------------------
extern "C" void kernel_launch(void* const* d_in, const int* in_sizes, int n_in,
                              void* d_out, int out_size, void* d_ws, size_t ws_size,
                              hipStream_t stream) {
  const void* x       = d_in[0];
  const void* theta_w = d_in[1];
  const void* theta_b = d_in[2];
  const void* phi_w   = d_in[3];
  const void* phi_b   = d_in[4];
  const void* g_w     = d_in[5];
  const void* g_b     = d_in[6];
  const void* W_w     = d_in[7];
  const void* W_b     = d_in[8];
  const void* gamma   = d_in[9];
  const void* beta    = d_in[10];

  char* wsb = (char*)d_ws;
  // round-3/7 layout exactly:
  //   [0, 16.78M)      xT -> ybuf
  //   [16.78M, 25.17M) theta -> W_y first half
  //   [25.17M, 33.55M) scratch (phi_c then g_c) -> W_y second half
  //   [33.55M, 35.65M) phi   [b][m][ci]
  //   [35.65M, 37.75M) gg    [b][ci][m]
  //   [37.75M+)        stats (512 f32), flag
  short* xT      = (short*)(wsb + 0);
  short* ybuf    = (short*)(wsb + 0);
  short* theta   = (short*)(wsb + 16777216);
  short* W_y     = (short*)(wsb + 16777216);
  short* scratch = (short*)(wsb + 25165824);
  short* phi     = (short*)(wsb + 33554432);
  short* gg      = (short*)(wsb + 35651584);
  float* stats   = (float*)(wsb + 37748736);
  int*   flag    = (int*)  (wsb + 37750784);

  dim3 blk(256);
  dim3 cgrid(64, 8);
  dim3 tgrid(64, 4, 8);

  hipMemsetAsync(stats, 0, 2048, stream);
  sniff_kernel<<<1, blk, 0, stream>>>((const unsigned short*)x, flag);
  transpose_x<<<tgrid, blk, 0, stream>>>(x, xT, flag);
  conv_t_k<<<cgrid, blk, 0, stream>>>(xT, theta_w, theta_b, theta, flag);
  conv_t_k<<<cgrid, blk, 0, stream>>>(xT, phi_w, phi_b, scratch, flag);
  pool_phi_kernel<<<4096, blk, 0, stream>>>(scratch, phi);
  conv_n_k<128, 256><<<cgrid, blk, 0, stream>>>(xT, g_w, g_b, scratch, flag);
  pool_g_kernel<<<4096, blk, 0, stream>>>(scratch, gg);
  attn_kernel<<<cgrid, blk, 0, stream>>>(theta, phi, gg, ybuf);
  convW_k<<<cgrid, blk, 0, stream>>>(ybuf, W_w, W_b, W_y, stats, flag);
  bn_apply4<<<8192, blk, 0, stream>>>(W_y, x, stats, gamma, beta, d_out, flag);
}